// Round 2
// baseline (3529.602 us; speedup 1.0000x reference)
//
#include <hip/hip_runtime.h>
#include <cmath>

// Problem constants (from reference): B=64, T=4096, D_IN=128, D_H=128, fp32.
#define BB   64
#define TT   4096
#define DIN  128
#define DH   128
#define GROWS 64   // rows of x per block in the precompute GEMM

// ---------------------------------------------------------------------------
// Kernel 1: P[n][j] = sum_k x[n][k] * Wx[k][j] + b[j],  n in [0, B*T)
// Written into d_out (same size as the final output); the scan kernel then
// consumes P and overwrites it in place with h.
// 256 threads = 2 row-groups x 128 columns. W_x column j lives in registers
// (128 VGPR); the 64x128 x-tile is staged in LDS and read via broadcast
// float4 loads (all lanes same address -> conflict-free).
// ---------------------------------------------------------------------------
__global__ __launch_bounds__(256) void xwx_gemm(const float* __restrict__ x,
                                                const float* __restrict__ Wx,
                                                const float* __restrict__ bias,
                                                float* __restrict__ P) {
    __shared__ float4 xs4[GROWS * DIN / 4];   // 32 KiB
    const int tid = threadIdx.x;
    const size_t row0 = (size_t)blockIdx.x * GROWS;

    // Stage x tile (coalesced float4 loads)
    const float4* xg = (const float4*)x + row0 * (DIN / 4);
#pragma unroll
    for (int i = 0; i < (GROWS * DIN / 4) / 256; ++i)
        xs4[tid + i * 256] = xg[tid + i * 256];

    const int j  = tid & (DH - 1);
    const int rg = tid >> 7;   // 0 or 1: which 32-row half

    // W_x column j -> registers (loads are coalesced across j at each k)
    float wj[DIN];
#pragma unroll
    for (int k = 0; k < DIN; ++k) wj[k] = Wx[k * DH + j];
    const float bj = bias[j];

    __syncthreads();

#pragma unroll 1
    for (int r = 0; r < GROWS / 2; ++r) {
        const float4* xr = xs4 + (rg * (GROWS / 2) + r) * (DIN / 4);
        float a0 = bj, a1 = 0.f, a2 = 0.f, a3 = 0.f;
#pragma unroll
        for (int k4 = 0; k4 < DIN / 4; ++k4) {
            float4 xv = xr[k4];
            a0 += xv.x * wj[4 * k4 + 0];
            a1 += xv.y * wj[4 * k4 + 1];
            a2 += xv.z * wj[4 * k4 + 2];
            a3 += xv.w * wj[4 * k4 + 3];
        }
        P[(row0 + rg * (GROWS / 2) + r) * DH + j] = (a0 + a1) + (a2 + a3);
    }
}

// ---------------------------------------------------------------------------
// Kernel 2: the sequential scan. One block per batch element (64 blocks),
// 128 threads; thread j owns output column j and holds W_h column j in
// registers. h is ping-pong buffered in LDS -> exactly ONE barrier per step.
// P (= x@Wx + b) is read from `po` with a 2-step register prefetch and the
// same buffer is overwritten in place with h_t: the load of po[t] is issued
// two iterations before the store to po[t], and the store's data depends on
// the loaded value, so the in-place update is race-free within the thread.
// ---------------------------------------------------------------------------
__global__ __launch_bounds__(128) void rnn_scan(float* po,   // P in, h out (aliased!)
                                                const float* __restrict__ Wh) {
    const int b = blockIdx.x;
    const int j = threadIdx.x;   // 0..127

    __shared__ float4 hbuf4[2][DH / 4];

    // W_h column j -> registers (coalesced across j at each k)
    float wj[DH];
#pragma unroll
    for (int k = 0; k < DH; ++k) wj[k] = Wh[k * DH + j];

    ((float*)hbuf4[0])[j] = 0.f;   // h_0 = 0

    float* pb = po + (size_t)b * TT * DH;
    float p0 = pb[j];          // P[t=0]
    float p1 = pb[DH + j];     // P[t=1]
    __syncthreads();

    int cur = 0;
#pragma unroll 2
    for (int t = 0; t < TT; ++t) {
        // Prefetch P[t+2] (guarded; select is cheap)
        float p2 = 0.f;
        if (t + 2 < TT) p2 = pb[(size_t)(t + 2) * DH + j];

        const float4* h4 = (const float4*)hbuf4[cur];
        float a0 = p0, a1 = 0.f, a2 = 0.f, a3 = 0.f;
#pragma unroll
        for (int k4 = 0; k4 < DH / 4; ++k4) {
            float4 hv = h4[k4];   // broadcast read: all lanes same address
            a0 += hv.x * wj[4 * k4 + 0];
            a1 += hv.y * wj[4 * k4 + 1];
            a2 += hv.z * wj[4 * k4 + 2];
            a3 += hv.w * wj[4 * k4 + 3];
        }
        float hnew = tanhf((a0 + a1) + (a2 + a3));

        pb[(size_t)t * DH + j] = hnew;            // output (overwrites P[t])
        ((float*)hbuf4[cur ^ 1])[j] = hnew;       // publish h_t
        __syncthreads();                          // one barrier per step
        cur ^= 1;
        p0 = p1;
        p1 = p2;
    }
}

extern "C" void kernel_launch(void* const* d_in, const int* in_sizes, int n_in,
                              void* d_out, int out_size, void* d_ws, size_t ws_size,
                              hipStream_t stream) {
    const float* x    = (const float*)d_in[0];   // (B, T, DIN)
    const float* Wx   = (const float*)d_in[1];   // (DIN, DH)
    const float* Wh   = (const float*)d_in[2];   // (DH, DH)
    const float* bias = (const float*)d_in[3];   // (DH,)
    float* out = (float*)d_out;                  // (B, T, DH)

    // Phase 1: P = x @ Wx + b  -> written into d_out
    const int nblk = (BB * TT) / GROWS;          // 4096 blocks
    xwx_gemm<<<nblk, 256, 0, stream>>>(x, Wx, bias, out);

    // Phase 2: sequential scan, in-place on d_out
    rnn_scan<<<BB, 128, 0, stream>>>(out, Wh);
}

// Round 3
// 2293.703 us; speedup vs baseline: 1.5388x; 1.5388x over previous
//
#include <hip/hip_runtime.h>
#include <cmath>

// Problem constants (from reference): B=64, T=4096, D_IN=128, D_H=128, fp32.
#define BB   64
#define TT   4096
#define DIN  128
#define DH   128
#define GROWS 64   // rows of x per block in the precompute GEMM

typedef float v2f __attribute__((ext_vector_type(2)));
typedef float v4f __attribute__((ext_vector_type(4)));

// Packed dual-fp32 FMA: acc = a*b + acc (VOP3P, gfx90a+/gfx950).
__device__ __forceinline__ void pk_fma(v2f& acc, v2f a, v2f b) {
    asm("v_pk_fma_f32 %0, %1, %2, %0" : "+v"(acc) : "v"(a), "v"(b));
}

// tanh(x) = 1 - 2/(exp2(2*log2e*x) + 1). Branch-free; x->+inf => 1, -inf => -1.
// exp2f maps to v_exp_f32 (+ocml edge handling); rcpf is the HW reciprocal.
__device__ __forceinline__ float fast_tanh(float x) {
    float e = exp2f(x * 2.885390081777927f);           // 2*log2(e)
    float r = __builtin_amdgcn_rcpf(e + 1.0f);
    return __builtin_fmaf(-2.0f, r, 1.0f);
}

// ---------------------------------------------------------------------------
// Kernel 1: P[n][j] = sum_k x[n][k]*Wx[k][j] + b[j]  -> written into d_out.
// 256 threads = 2 row-groups x 128 cols. Wx column j held in 64 PINNED float2
// VGPR pairs (asm keep-alive defeats rematerialization); x tile staged in LDS
// and read via wave-broadcast float4 (conflict-free). pk-FMA halves issue.
// ---------------------------------------------------------------------------
__global__ __launch_bounds__(256, 2) void xwx_gemm(const float* __restrict__ x,
                                                   const float* __restrict__ Wx,
                                                   const float* __restrict__ bias,
                                                   float* __restrict__ P) {
    __shared__ v4f xs4[GROWS * DIN / 4];   // 32 KiB
    const int tid = threadIdx.x;
    const size_t row0 = (size_t)blockIdx.x * GROWS;

    // Stage x tile (coalesced float4 loads)
    const v4f* xg = (const v4f*)x + row0 * (DIN / 4);
#pragma unroll
    for (int i = 0; i < (GROWS * DIN / 4) / 256; ++i)
        xs4[tid + i * 256] = xg[tid + i * 256];

    const int j  = tid & (DH - 1);
    const int rg = tid >> 7;   // 0 or 1: which 32-row half

    // Wx column j -> 64 pinned float2 (k-pairs)
    v2f wj2[DIN / 2];
#pragma unroll
    for (int m = 0; m < DIN / 2; ++m) {
        v2f w;
        w.x = Wx[(2 * m + 0) * DH + j];
        w.y = Wx[(2 * m + 1) * DH + j];
        wj2[m] = w;
        asm("" : "+v"(wj2[m]));   // pin in VGPRs; forbid remat-as-reload
    }
    const float bj = bias[j];

    __syncthreads();

#pragma unroll 1
    for (int r = 0; r < GROWS / 2; ++r) {
        const v4f* xr = xs4 + (rg * (GROWS / 2) + r) * (DIN / 4);
        v2f a0 = {0.f, 0.f}, a1 = {0.f, 0.f}, a2 = {0.f, 0.f}, a3 = {0.f, 0.f};
#pragma unroll
        for (int k4 = 0; k4 < DIN / 4; k4 += 2) {
            v4f ha = xr[k4];       // broadcast ds_read_b128
            v4f hb = xr[k4 + 1];
            v2f ha01 = {ha.x, ha.y}, ha23 = {ha.z, ha.w};
            v2f hb01 = {hb.x, hb.y}, hb23 = {hb.z, hb.w};
            pk_fma(a0, ha01, wj2[2 * k4 + 0]);
            pk_fma(a1, ha23, wj2[2 * k4 + 1]);
            pk_fma(a2, hb01, wj2[2 * k4 + 2]);
            pk_fma(a3, hb23, wj2[2 * k4 + 3]);
        }
        float s = ((a0.x + a0.y) + (a1.x + a1.y)) + ((a2.x + a2.y) + (a3.x + a3.y));
        P[(row0 + rg * (GROWS / 2) + r) * DH + j] = s + bj;
    }
}

// ---------------------------------------------------------------------------
// Kernel 2: sequential scan. One block per batch (64 blocks), 128 threads
// (2 waves); thread j owns column j, W_h column j in 64 PINNED float2 pairs.
// h ping-pongs in LDS with ONE LDS-only barrier per step:
//   asm "s_waitcnt lgkmcnt(0); s_barrier"  -- does NOT drain vmcnt, so the
// 8-step batched P prefetch and the output stores stay in flight across
// steps (the __syncthreads vmcnt(0) drain was the 1687-cyc/step killer).
// P is read from `po` and overwritten in place with h (loads for steps
// [tg+8,tg+16) are issued before the stores to [tg,tg+8); disjoint t).
// ---------------------------------------------------------------------------
__global__ __launch_bounds__(128, 1) void rnn_scan(float* po,   // P in, h out (aliased!)
                                                   const float* __restrict__ Wh) {
    const int b = blockIdx.x;
    const int j = threadIdx.x;   // 0..127

    __shared__ v4f hbuf[2][DH / 4];

    // W_h column j -> 64 pinned float2 (k-pairs)
    v2f wj2[DH / 2];
#pragma unroll
    for (int m = 0; m < DH / 2; ++m) {
        v2f w;
        w.x = Wh[(2 * m + 0) * DH + j];
        w.y = Wh[(2 * m + 1) * DH + j];
        wj2[m] = w;
        asm("" : "+v"(wj2[m]));   // pin in VGPRs; forbid remat-as-reload
    }

    float* pbB = po + (size_t)b * TT * DH + j;

    // First P batch (steps 0..7)
    float pc[8], pn[8];
#pragma unroll
    for (int i = 0; i < 8; ++i) pc[i] = pbB[(size_t)i * DH];

    ((float*)hbuf[0])[j] = 0.f;   // h_0 = 0
    __syncthreads();              // once; full drain harmless here

    int cur = 0;
#pragma unroll 1
    for (int tg = 0; tg < TT; tg += 8) {
        // Issue next P batch (fire-and-forget; consumed 8 steps later).
        // Clamp keeps the address valid on the last group (values unused).
#pragma unroll
        for (int i = 0; i < 8; ++i) {
            int tl = tg + 8 + i;
            tl = (tl < TT) ? tl : (TT - 1);
            pn[i] = pbB[(size_t)tl * DH];
        }

#pragma unroll
        for (int u = 0; u < 8; ++u) {
            const int t = tg + u;
            const v4f* h4 = hbuf[cur];
            v2f a0 = {pc[u], 0.f}, a1 = {0.f, 0.f}, a2 = {0.f, 0.f}, a3 = {0.f, 0.f};
#pragma unroll
            for (int k4 = 0; k4 < DH / 4; k4 += 2) {
                v4f ha = h4[k4];       // broadcast ds_read_b128
                v4f hb = h4[k4 + 1];
                v2f ha01 = {ha.x, ha.y}, ha23 = {ha.z, ha.w};
                v2f hb01 = {hb.x, hb.y}, hb23 = {hb.z, hb.w};
                pk_fma(a0, ha01, wj2[2 * k4 + 0]);
                pk_fma(a1, ha23, wj2[2 * k4 + 1]);
                pk_fma(a2, hb01, wj2[2 * k4 + 2]);
                pk_fma(a3, hb23, wj2[2 * k4 + 3]);
            }
            float s = ((a0.x + a0.y) + (a1.x + a1.y)) + ((a2.x + a2.y) + (a3.x + a3.y));
            float hnew = fast_tanh(s);

            pbB[(size_t)t * DH] = hnew;           // output (overwrites P[t]); never drained
            ((float*)hbuf[cur ^ 1])[j] = hnew;    // publish h_t

            // LDS-only barrier: wait own ds_write, sync waves; vmcnt untouched.
            asm volatile("s_waitcnt lgkmcnt(0)\n\ts_barrier" ::: "memory");
            cur ^= 1;
        }

#pragma unroll
        for (int i = 0; i < 8; ++i) pc[i] = pn[i];   // register rotate
    }
}

extern "C" void kernel_launch(void* const* d_in, const int* in_sizes, int n_in,
                              void* d_out, int out_size, void* d_ws, size_t ws_size,
                              hipStream_t stream) {
    const float* x    = (const float*)d_in[0];   // (B, T, DIN)
    const float* Wx   = (const float*)d_in[1];   // (DIN, DH)
    const float* Wh   = (const float*)d_in[2];   // (DH, DH)
    const float* bias = (const float*)d_in[3];   // (DH,)
    float* out = (float*)d_out;                  // (B, T, DH)

    // Phase 1: P = x @ Wx + b  -> written into d_out
    const int nblk = (BB * TT) / GROWS;          // 4096 blocks
    xwx_gemm<<<nblk, 256, 0, stream>>>(x, Wx, bias, out);

    // Phase 2: sequential scan, in-place on d_out
    rnn_scan<<<BB, 128, 0, stream>>>(out, Wh);
}